// Round 1
// baseline (275.775 us; speedup 1.0000x reference)
//
#include <hip/hip_runtime.h>
#include <math.h>

// Problem constants
#define BB 128
#define NN 2000
#define CC 100
#define DD 128
#define NSPLIT 16          // node-sum splits per batch
#define NEGV -1000000000.0f

// Workspace layout (float offsets). Total ~2.35M floats = 9.4 MB.
#define OFF_P1   0                              // partial sum1: B*16*128
#define OFF_P2   (OFF_P1 + BB*NSPLIT*DD)        // partial sum2: B*16*128
#define OFF_WQQ  (OFF_P2 + BB*NSPLIT*DD)        // Wq@Wmq: 384*128
#define OFF_WKV  (OFF_WQQ + 384*DD)             // [Wk@Wmk | Wv@Wmv]: 128*256
#define OFF_SC   (OFF_WKV + DD*256)             // scores: B*8*100
#define OFF_VH   (OFF_SC + BB*8*CC)             // vh: B*100*128

// Output layout (float offsets into d_out)
#define OUT_AUG 0                 // (B,1,512)
#define OUT_GE  (BB*512)          // (B,1,128)
#define OUT_GU  (OUT_GE + BB*DD)  // (B,) guidance written as float
#define OUT_CP  (OUT_GU + BB)     // (B,100)

// ---------------------------------------------------------------------------
// K1: fused-weight precompute (blocks 0..79) + masked node sums (blocks 80..)
// ---------------------------------------------------------------------------
__global__ __launch_bounds__(256) void k_prep_sums(
    const float* __restrict__ node, const int* __restrict__ mask,
    const int* __restrict__ cmask, const int* __restrict__ is_new,
    const float* __restrict__ Wq, const float* __restrict__ Wmq,
    const float* __restrict__ Wk, const float* __restrict__ Wmk,
    const float* __restrict__ Wv, const float* __restrict__ Wmv,
    float* __restrict__ ws)
{
    int t = threadIdx.x;
    int blk = blockIdx.x;

    if (blk < 80) {
        // Fused weight products: Wqq = Wq@Wmq (48 blocks), Wkk (16), Wvv (16).
        const float *W1, *W2;
        float* wout; int rbase, ostride, ooff;
        if (blk < 48)      { W1 = Wq; W2 = Wmq; wout = ws + OFF_WQQ; rbase = blk*8;      ostride = 128; ooff = 0;   }
        else if (blk < 64) { W1 = Wk; W2 = Wmk; wout = ws + OFF_WKV; rbase = (blk-48)*8; ostride = 256; ooff = 0;   }
        else               { W1 = Wv; W2 = Wmv; wout = ws + OFF_WKV; rbase = (blk-64)*8; ostride = 256; ooff = 128; }
        int j = t & 127, r0 = t >> 7;   // 8 rows per block: r0 + {0,2,4,6}
        float a0 = 0.f, a1 = 0.f, a2 = 0.f, a3 = 0.f;
        for (int k = 0; k < 128; k++) {
            float b2 = W2[k*128 + j];
            a0 += W1[(rbase + r0 + 0)*128 + k] * b2;
            a1 += W1[(rbase + r0 + 2)*128 + k] * b2;
            a2 += W1[(rbase + r0 + 4)*128 + k] * b2;
            a3 += W1[(rbase + r0 + 6)*128 + k] * b2;
        }
        wout[(rbase + r0 + 0)*ostride + ooff + j] = a0;
        wout[(rbase + r0 + 2)*ostride + ooff + j] = a1;
        wout[(rbase + r0 + 4)*ostride + ooff + j] = a2;
        wout[(rbase + r0 + 6)*ostride + ooff + j] = a3;
        return;
    }

    // Node partial sums. grid: NSPLIT chunks x B batches.
    int idx = blk - 80;
    int b = idx >> 4, s = idx & 15;
    if (!is_new[b]) return;   // all outputs zero for this batch -> skip 131MB scan

    int lane = t & 31, q = t >> 5;   // 8 row-groups x 32 lanes (float4 per lane)
    float a1x=0,a1y=0,a1z=0,a1w=0, a2x=0,a2y=0,a2z=0,a2w=0;
    int n0 = s * 125;
    for (int r = q; r < 125; r += 8) {
        int n = n0 + r;
        if (mask[b*NN + n]) continue;            // excluded from both sums: skip load
        const float4 x = *(const float4*)(node + ((size_t)b*NN + n)*DD + lane*4);
        a1x += x.x; a1y += x.y; a1z += x.z; a1w += x.w;
        if (!cmask[b*NN + n]) { a2x += x.x; a2y += x.y; a2z += x.z; a2w += x.w; }
    }
    __shared__ float s1[8][128];
    __shared__ float s2[8][128];
    s1[q][lane*4+0] = a1x; s1[q][lane*4+1] = a1y; s1[q][lane*4+2] = a1z; s1[q][lane*4+3] = a1w;
    s2[q][lane*4+0] = a2x; s2[q][lane*4+1] = a2y; s2[q][lane*4+2] = a2z; s2[q][lane*4+3] = a2w;
    __syncthreads();
    if (t < 128) {
        float v = 0.f;
        for (int qq = 0; qq < 8; qq++) v += s1[qq][t];
        ws[OFF_P1 + (b*NSPLIT + s)*DD + t] = v;
    } else {
        int d = t - 128;
        float v = 0.f;
        for (int qq = 0; qq < 8; qq++) v += s2[qq][d];
        ws[OFF_P2 + (b*NSPLIT + s)*DD + d] = v;
    }
}

// ---------------------------------------------------------------------------
// K2a: per (batch, 25-cluster chunk): kh/vh = cluster@(Wkk|Wvv), scores=qh.kh/4
// ---------------------------------------------------------------------------
__global__ __launch_bounds__(256) void k_cluster(
    const float* __restrict__ cluster, const float* __restrict__ current,
    const float* __restrict__ depot, const int* __restrict__ is_new,
    float* __restrict__ ws)
{
    int b = blockIdx.y;
    if (!is_new[b]) return;
    int t = threadIdx.x;
    const float* part1 = ws + OFF_P1;
    const float* Wqq   = ws + OFF_WQQ;
    const float* Wkv   = ws + OFF_WKV;
    float* scores      = ws + OFF_SC;
    float* vh          = ws + OFF_VH;

    __shared__ float ctx[384];
    __shared__ float qh_s[128];
    __shared__ float rowbuf[25*128];

    if (t < 128) {
        float v = 0.f;
        for (int s = 0; s < NSPLIT; s++) v += part1[(b*NSPLIT + s)*DD + t];
        ctx[t]       = v * (1.0f/2000.0f);     // unvisit_mean
        ctx[256 + t] = depot[b*DD + t];
    } else {
        ctx[t] = current[b*DD + (t - 128)];    // ctx[128..255]
    }
    int base = blockIdx.x * 25;
    for (int idx = t; idx < 25*128; idx += 256)
        rowbuf[idx] = cluster[((size_t)b*CC + base + (idx >> 7))*DD + (idx & 127)];
    __syncthreads();

    if (t < 128) {   // qh = context @ Wqq
        float a = 0.f;
        for (int r = 0; r < 384; r++) a += ctx[r] * Wqq[r*128 + t];
        qh_s[t] = a;
    }
    __syncthreads();

    // Register tile: 4 col-groups (g = t>>6) x rows {g,g+4,...}, 4 cols/thread.
    int g = t >> 6, l = t & 63;
    float acc[6][4];
    float acc6[4] = {0.f,0.f,0.f,0.f};
    #pragma unroll
    for (int m = 0; m < 6; m++) { acc[m][0]=0.f; acc[m][1]=0.f; acc[m][2]=0.f; acc[m][3]=0.f; }
    bool has7 = (g == 0);   // row 24 handled by group 0 only (wave-uniform)

    for (int i = 0; i < 128; i++) {
        float w0 = Wkv[i*256 +   0 + l];
        float w1 = Wkv[i*256 +  64 + l];
        float w2 = Wkv[i*256 + 128 + l];
        float w3 = Wkv[i*256 + 192 + l];
        #pragma unroll
        for (int m = 0; m < 6; m++) {
            float x = rowbuf[(g + 4*m)*128 + i];
            acc[m][0] += x*w0; acc[m][1] += x*w1; acc[m][2] += x*w2; acc[m][3] += x*w3;
        }
        if (has7) {
            float x = rowbuf[24*128 + i];
            acc6[0] += x*w0; acc6[1] += x*w1; acc6[2] += x*w2; acc6[3] += x*w3;
        }
    }

    #pragma unroll
    for (int m = 0; m < 7; m++) {
        int row = g + 4*m;
        if (row >= 25) break;
        float* a = (m < 6) ? acc[m] : acc6;
        int c = base + row;
        vh[((size_t)b*CC + c)*128 +      l] = a[2];
        vh[((size_t)b*CC + c)*128 + 64 + l] = a[3];
        float p0 = a[0] * qh_s[l];
        float p1 = a[1] * qh_s[64 + l];
        p0 += __shfl_xor(p0, 1); p0 += __shfl_xor(p0, 2); p0 += __shfl_xor(p0, 4); p0 += __shfl_xor(p0, 8);
        p1 += __shfl_xor(p1, 1); p1 += __shfl_xor(p1, 2); p1 += __shfl_xor(p1, 4); p1 += __shfl_xor(p1, 8);
        if ((l & 15) == 0) {
            scores[(b*8 +     (l >> 4))*CC + c] = p0 * 0.25f;   // heads 0..3
            scores[(b*8 + 4 + (l >> 4))*CC + c] = p1 * 0.25f;   // heads 4..7
        }
    }
}

// ---------------------------------------------------------------------------
// K2b: per-batch softmax -> glimpse -> logits -> argmax -> all outputs
// ---------------------------------------------------------------------------
__global__ __launch_bounds__(256) void k_final(
    const float* __restrict__ cluster, const float* __restrict__ current,
    const float* __restrict__ depot, const int* __restrict__ is_new,
    const int* __restrict__ visited, const float* __restrict__ Wks,
    const float* __restrict__ Wmo, float* __restrict__ ws,
    float* __restrict__ out)
{
    int b = blockIdx.x;
    int t = threadIdx.x;

    if (!is_new[b]) {   // every output exactly 0 (d_out is poisoned -> must write)
        for (int k = t; k < 512; k += 256) out[OUT_AUG + b*512 + k] = 0.f;
        if (t < 128) out[OUT_GE + b*DD + t] = 0.f;
        if (t == 0)  out[OUT_GU + b] = 0.f;
        if (t < 100) out[OUT_CP + b*CC + t] = 0.f;
        return;
    }

    const float* part2  = ws + OFF_P2;
    const float* scores = ws + OFF_SC;
    const float* vh     = ws + OFF_VH;

    __shared__ int   vcm_s[CC];
    __shared__ int   allv;
    __shared__ float attn[8][CC];
    __shared__ float gtmp[2][128];
    __shared__ float g_s[128], g1_s[128], g2_s[128];
    __shared__ float lg[CC];
    __shared__ int   g_idx;
    __shared__ float lse_s;

    if (t < CC) vcm_s[t] = (visited[b*CC + t] != 0);
    if (t == 0) allv = 1;
    __syncthreads();
    if (t >= 1 && t < CC && !vcm_s[t]) allv = 0;   // benign same-value race
    __syncthreads();
    if (t == 0) vcm_s[0] = allv ? 0 : 1;           // is_new: vcm0 = !all_vis
    __syncthreads();

    // Per-head softmax: 8 heads x 32 lanes
    {
        int h = t >> 5, l = t & 31;
        float smax = -1e30f;
        for (int c = l; c < CC; c += 32) {
            float v = scores[(b*8 + h)*CC + c];
            v = vcm_s[c] ? NEGV : v;
            attn[h][c] = v;
            smax = fmaxf(smax, v);
        }
        for (int o = 1; o < 32; o <<= 1) smax = fmaxf(smax, __shfl_xor(smax, o));
        float ssum = 0.f;
        for (int c = l; c < CC; c += 32) { float e = expf(attn[h][c] - smax); attn[h][c] = e; ssum += e; }
        for (int o = 1; o < 32; o <<= 1) ssum += __shfl_xor(ssum, o);
        float inv = 1.0f / ssum;
        for (int c = l; c < CC; c += 32) attn[h][c] *= inv;
    }
    __syncthreads();

    // glimpse[j] = sum_c attn[h(j)][c] * vh[c][j]
    {
        int j = t & 127, half = t >> 7;
        float gacc = 0.f;
        for (int c = half*50; c < half*50 + 50; c++)
            gacc += attn[j >> 4][c] * vh[((size_t)b*CC + c)*128 + j];
        gtmp[half][j] = gacc;
    }
    __syncthreads();
    if (t < 128) g_s[t] = gtmp[0][t] + gtmp[1][t];
    __syncthreads();
    if (t < 128) {   // g1 = glimpse @ Wmo
        float a = 0.f;
        for (int i = 0; i < 128; i++) a += g_s[i] * Wmo[i*128 + t];
        g1_s[t] = a;
    }
    __syncthreads();
    if (t < 128) {   // g2[i] = sum_d Wks[i][d]*g1[d], fold 1/sqrt(128)
        float a = 0.f;
        for (int d = 0; d < 128; d++) a += Wks[t*128 + d] * g1_s[d];
        g2_s[t] = a * 0.08838834764831845f;
    }
    __syncthreads();
    // logits: 2 threads per cluster
    if (t < 200) {
        int c = t >> 1, hf = t & 1;
        const float* cr = cluster + ((size_t)b*CC + c)*DD + hf*64;
        float a = 0.f;
        for (int i = 0; i < 64; i++) a += g2_s[hf*64 + i] * cr[i];
        a += __shfl_xor(a, 1);
        if (!hf) lg[c] = vcm_s[c] ? NEGV : 10.0f * tanhf(a);
    }
    __syncthreads();
    // log-softmax denom + first-occurrence argmax (numpy semantics)
    if (t < 32) {
        float bv = -1e30f; int bi = 0;
        for (int c = t; c < CC; c += 32) { float v = lg[c]; if (v > bv) { bv = v; bi = c; } }
        for (int o = 1; o < 32; o <<= 1) {
            float ov = __shfl_xor(bv, o); int oi = __shfl_xor(bi, o);
            if (ov > bv || (ov == bv && oi < bi)) { bv = ov; bi = oi; }
        }
        float se = 0.f;
        for (int c = t; c < CC; c += 32) se += expf(lg[c] - bv);
        for (int o = 1; o < 32; o <<= 1) se += __shfl_xor(se, o);
        if (t == 0) { g_idx = bi; lse_s = bv + logf(se); }
    }
    __syncthreads();

    int gi = g_idx; float lse = lse_s;
    if (t < CC)  out[OUT_CP + b*CC + t] = lg[t] - lse;
    if (t == 0)  out[OUT_GU + b] = (float)gi;
    if (t < 128) {
        float ge = cluster[((size_t)b*CC + gi)*DD + t];
        out[OUT_GE + b*DD + t] = ge;
        float uc = 0.f;
        for (int s = 0; s < NSPLIT; s++) uc += part2[(b*NSPLIT + s)*DD + t];
        out[OUT_AUG + b*512 +       t] = uc * (1.0f/2000.0f);  // unvisit_cluster
        out[OUT_AUG + b*512 + 128 + t] = current[b*DD + t];
        out[OUT_AUG + b*512 + 256 + t] = ge;
        out[OUT_AUG + b*512 + 384 + t] = depot[b*DD + t];
    }
}

extern "C" void kernel_launch(void* const* d_in, const int* in_sizes, int n_in,
                              void* d_out, int out_size, void* d_ws, size_t ws_size,
                              hipStream_t stream) {
    const float* depot   = (const float*)d_in[0];
    const float* cluster = (const float*)d_in[1];
    const float* current = (const float*)d_in[2];
    const float* node    = (const float*)d_in[3];
    const int*   is_new  = (const int*)d_in[4];
    const int*   cmask   = (const int*)d_in[5];
    const int*   visited = (const int*)d_in[6];
    const int*   mask    = (const int*)d_in[7];
    const float* Wq  = (const float*)d_in[8];
    const float* Wk  = (const float*)d_in[9];
    const float* Wv  = (const float*)d_in[10];
    const float* Wks = (const float*)d_in[11];
    const float* Wmq = (const float*)d_in[12];
    const float* Wmk = (const float*)d_in[13];
    const float* Wmv = (const float*)d_in[14];
    const float* Wmo = (const float*)d_in[15];
    float* ws  = (float*)d_ws;
    float* out = (float*)d_out;

    k_prep_sums<<<80 + BB*NSPLIT, 256, 0, stream>>>(node, mask, cmask, is_new,
                                                    Wq, Wmq, Wk, Wmk, Wv, Wmv, ws);
    k_cluster<<<dim3(4, BB), 256, 0, stream>>>(cluster, current, depot, is_new, ws);
    k_final<<<BB, 256, 0, stream>>>(cluster, current, depot, is_new, visited,
                                    Wks, Wmo, ws, out);
}

// Round 2
// 242.724 us; speedup vs baseline: 1.1362x; 1.1362x over previous
//
#include <hip/hip_runtime.h>
#include <math.h>

// Problem constants
#define BB 128
#define NN 2000
#define CC 100
#define DD 128
#define NSPLIT 16
#define NEGV -1000000000.0f
#define CSTRIDE 129   // padded LDS stride for cluster tile (kills 32-bank aliasing)

// Workspace layout (float offsets)
#define OFF_P1   0                              // partial sum1: B*16*128
#define OFF_P2   (OFF_P1 + BB*NSPLIT*DD)        // partial sum2: B*16*128
#define OFF_WQQ  (OFF_P2 + BB*NSPLIT*DD)        // Wq@Wmq: 384*128
#define OFF_WKV  (OFF_WQQ + 384*DD)             // [Wk@Wmk | Wv@Wmv]: 128*256

// Output layout (float offsets into d_out)
#define OUT_AUG 0                 // (B,1,512)
#define OUT_GE  (BB*512)          // (B,1,128)
#define OUT_GU  (OUT_GE + BB*DD)  // (B,) guidance as float
#define OUT_CP  (OUT_GU + BB)     // (B,100)

// ---------------------------------------------------------------------------
// K1: fused-weight precompute (blocks 0..79) + masked node sums (blocks 80..)
// ---------------------------------------------------------------------------
__global__ __launch_bounds__(256) void k_prep_sums(
    const float* __restrict__ node, const int* __restrict__ mask,
    const int* __restrict__ cmask, const int* __restrict__ is_new,
    const float* __restrict__ Wq, const float* __restrict__ Wmq,
    const float* __restrict__ Wk, const float* __restrict__ Wmk,
    const float* __restrict__ Wv, const float* __restrict__ Wmv,
    float* __restrict__ ws)
{
    int t = threadIdx.x;
    int blk = blockIdx.x;

    if (blk < 80) {
        const float *W1, *W2;
        float* wout; int rbase, ostride, ooff;
        if (blk < 48)      { W1 = Wq; W2 = Wmq; wout = ws + OFF_WQQ; rbase = blk*8;      ostride = 128; ooff = 0;   }
        else if (blk < 64) { W1 = Wk; W2 = Wmk; wout = ws + OFF_WKV; rbase = (blk-48)*8; ostride = 256; ooff = 0;   }
        else               { W1 = Wv; W2 = Wmv; wout = ws + OFF_WKV; rbase = (blk-64)*8; ostride = 256; ooff = 128; }
        int j = t & 127, r0 = t >> 7;   // rows r0 + {0,2,4,6}
        float a0 = 0.f, a1 = 0.f, a2 = 0.f, a3 = 0.f;
        for (int k = 0; k < 128; k++) {
            float b2 = W2[k*128 + j];
            a0 += W1[(rbase + r0 + 0)*128 + k] * b2;
            a1 += W1[(rbase + r0 + 2)*128 + k] * b2;
            a2 += W1[(rbase + r0 + 4)*128 + k] * b2;
            a3 += W1[(rbase + r0 + 6)*128 + k] * b2;
        }
        wout[(rbase + r0 + 0)*ostride + ooff + j] = a0;
        wout[(rbase + r0 + 2)*ostride + ooff + j] = a1;
        wout[(rbase + r0 + 4)*ostride + ooff + j] = a2;
        wout[(rbase + r0 + 6)*ostride + ooff + j] = a3;
        return;
    }

    int idx = blk - 80;
    int b = idx >> 4, s = idx & 15;
    if (!is_new[b]) return;   // outputs all-zero for this batch: skip the scan

    int lane = t & 31, q = t >> 5;
    float a1x=0,a1y=0,a1z=0,a1w=0, a2x=0,a2y=0,a2z=0,a2w=0;
    int n0 = s * 125;
    for (int r = q; r < 125; r += 8) {
        int n = n0 + r;
        if (mask[b*NN + n]) continue;
        const float4 x = *(const float4*)(node + ((size_t)b*NN + n)*DD + lane*4);
        a1x += x.x; a1y += x.y; a1z += x.z; a1w += x.w;
        if (!cmask[b*NN + n]) { a2x += x.x; a2y += x.y; a2z += x.z; a2w += x.w; }
    }
    __shared__ float s1[8][128];
    __shared__ float s2[8][128];
    s1[q][lane*4+0] = a1x; s1[q][lane*4+1] = a1y; s1[q][lane*4+2] = a1z; s1[q][lane*4+3] = a1w;
    s2[q][lane*4+0] = a2x; s2[q][lane*4+1] = a2y; s2[q][lane*4+2] = a2z; s2[q][lane*4+3] = a2w;
    __syncthreads();
    if (t < 128) {
        float v = 0.f;
        for (int qq = 0; qq < 8; qq++) v += s1[qq][t];
        ws[OFF_P1 + (b*NSPLIT + s)*DD + t] = v;
    } else {
        int d = t - 128;
        float v = 0.f;
        for (int qq = 0; qq < 8; qq++) v += s2[qq][d];
        ws[OFF_P2 + (b*NSPLIT + s)*DD + d] = v;
    }
}

// ---------------------------------------------------------------------------
// K2 (fused): per-batch everything. Never materializes kh/vh:
//   score[h][c] = clu[c] . u_h,  u_h = Wkk @ qh_h          (factored)
//   glimpse     = (sum_c attn[h][c] clu[c]) @ Wvv          (factored)
// ---------------------------------------------------------------------------
__global__ __launch_bounds__(256) void k_fused(
    const float* __restrict__ cluster, const float* __restrict__ current,
    const float* __restrict__ depot, const int* __restrict__ is_new,
    const int* __restrict__ visited, const float* __restrict__ Wks,
    const float* __restrict__ Wmo, const float* __restrict__ ws,
    float* __restrict__ out)
{
    int b = blockIdx.x;
    int t = threadIdx.x;

    if (!is_new[b]) {   // every output exactly 0 (d_out poisoned -> must write)
        for (int k = t; k < 512; k += 256) out[OUT_AUG + b*512 + k] = 0.f;
        if (t < 128) out[OUT_GE + b*DD + t] = 0.f;
        if (t == 0)  out[OUT_GU + b] = 0.f;
        if (t < 100) out[OUT_CP + b*CC + t] = 0.f;
        return;
    }

    const float* part1 = ws + OFF_P1;
    const float* part2 = ws + OFF_P2;
    const float* Wqq   = ws + OFF_WQQ;
    const float* Wkv   = ws + OFF_WKV;

    __shared__ float clu[CC*CSTRIDE];      // 51.6 KB
    __shared__ float ctx[384];
    __shared__ float qtmp[2][128];
    __shared__ float qh_s[128];
    __shared__ float uT[128*8];            // u transposed: uT[i*8+h], 0.25 folded
    __shared__ float sT[CC*9];             // scores then attn, [c*9+h]
    __shared__ float wS[8*128];            // attn-weighted cluster sums
    __shared__ float g_s[128], g1_s[128], g2_s[128];
    __shared__ float lg[CC];
    __shared__ int   vcm_s[CC];
    __shared__ int   allv;
    __shared__ int   g_idx;
    __shared__ float lse_s;

    // P0: context, vcm, cluster tile
    if (t < 128) {
        float v = 0.f;
        for (int s = 0; s < NSPLIT; s++) v += part1[(b*NSPLIT + s)*DD + t];
        ctx[t]       = v * (1.0f/2000.0f);
        ctx[256 + t] = depot[b*DD + t];
    } else {
        ctx[t] = current[b*DD + (t - 128)];
    }
    if (t < CC) vcm_s[t] = (visited[b*CC + t] != 0);
    if (t == 0) allv = 1;
    for (int idx = t; idx < CC*DD; idx += 256)
        clu[(idx >> 7)*CSTRIDE + (idx & 127)] = cluster[(size_t)b*CC*DD + idx];
    __syncthreads();
    if (t >= 1 && t < CC && !vcm_s[t]) allv = 0;   // benign same-value race
    __syncthreads();
    if (t == 0) vcm_s[0] = allv ? 0 : 1;           // is_new: vcm0 = !all_vis

    // P1: qh = ctx @ Wqq (split K over 2 halves)
    {
        int j = t & 127, half = t >> 7;
        float a = 0.f;
        for (int r = half*192; r < half*192 + 192; r++) a += ctx[r] * Wqq[r*128 + j];
        qtmp[half][j] = a;
    }
    __syncthreads();
    if (t < 128) qh_s[t] = qtmp[0][t] + qtmp[1][t];
    __syncthreads();

    // P2: u_h[i] = sum_dk Wkk[i][h*16+dk]*qh[h*16+dk], fold 1/sqrt(DK)=0.25
    {
        int i = t & 127, hq = t >> 7;   // 4 heads per thread
        #pragma unroll
        for (int hh = 0; hh < 4; hh++) {
            int h = hq*4 + hh;
            float a = 0.f;
            #pragma unroll
            for (int dk = 0; dk < 16; dk++)
                a += Wkv[i*256 + h*16 + dk] * qh_s[h*16 + dk];
            uT[i*8 + h] = a * 0.25f;
        }
    }
    __syncthreads();

    // P3: scores[c][h] = clu[c] . u_h  (2 threads per c, i-split)
    if (t < 200) {
        int c = t >> 1, ih = t & 1;
        float s0=0,s1=0,s2=0,s3=0,s4=0,s5=0,s6=0,s7=0;
        for (int i = ih*64; i < ih*64 + 64; i++) {
            float x = clu[c*CSTRIDE + i];
            const float* u = &uT[i*8];
            s0 += x*u[0]; s1 += x*u[1]; s2 += x*u[2]; s3 += x*u[3];
            s4 += x*u[4]; s5 += x*u[5]; s6 += x*u[6]; s7 += x*u[7];
        }
        s0 += __shfl_xor(s0,1); s1 += __shfl_xor(s1,1); s2 += __shfl_xor(s2,1); s3 += __shfl_xor(s3,1);
        s4 += __shfl_xor(s4,1); s5 += __shfl_xor(s5,1); s6 += __shfl_xor(s6,1); s7 += __shfl_xor(s7,1);
        if (!ih) {
            float* d = &sT[c*9];
            d[0]=s0; d[1]=s1; d[2]=s2; d[3]=s3; d[4]=s4; d[5]=s5; d[6]=s6; d[7]=s7;
        }
    }
    __syncthreads();

    // P4: per-head softmax (8 heads x 32 lanes), in-place sT -> attn
    {
        int h = t >> 5, l = t & 31;
        float vals[4]; int nv = 0;
        float smax = -1e30f;
        for (int c = l; c < CC; c += 32) {
            float v = vcm_s[c] ? NEGV : sT[c*9 + h];
            vals[nv++] = v;
            smax = fmaxf(smax, v);
        }
        for (int o = 1; o < 32; o <<= 1) smax = fmaxf(smax, __shfl_xor(smax, o));
        float ssum = 0.f; nv = 0;
        for (int c = l; c < CC; c += 32) { float e = expf(vals[nv] - smax); vals[nv++] = e; ssum += e; }
        for (int o = 1; o < 32; o <<= 1) ssum += __shfl_xor(ssum, o);
        float inv = 1.0f / ssum; nv = 0;
        for (int c = l; c < CC; c += 32) sT[c*9 + h] = vals[nv++] * inv;
    }
    __syncthreads();

    // P5: w_h[i] = sum_c attn[h][c] * clu[c][i]
    {
        int i = t & 127, hq = t >> 7;
        float a0=0,a1=0,a2=0,a3=0;
        int h0 = hq*4;
        for (int c = 0; c < CC; c++) {
            float x = clu[c*CSTRIDE + i];
            const float* at = &sT[c*9 + h0];
            a0 += x*at[0]; a1 += x*at[1]; a2 += x*at[2]; a3 += x*at[3];
        }
        wS[(h0+0)*128 + i] = a0; wS[(h0+1)*128 + i] = a1;
        wS[(h0+2)*128 + i] = a2; wS[(h0+3)*128 + i] = a3;
    }
    __syncthreads();

    // P6: glimpse[j] = w_{j>>4} . Wvv[:,j]
    if (t < 128) {
        int h = t >> 4;
        float a = 0.f;
        for (int i = 0; i < 128; i++) a += wS[h*128 + i] * Wkv[i*256 + 128 + t];
        g_s[t] = a;
    }
    __syncthreads();
    // P7: g1 = glimpse @ Wmo
    if (t < 128) {
        float a = 0.f;
        for (int i = 0; i < 128; i++) a += g_s[i] * Wmo[i*128 + t];
        g1_s[t] = a;
    }
    __syncthreads();
    // P8: g2[d] = (Wks[d,:] . g1) / sqrt(128)  (per-thread contiguous row, L2-hot)
    if (t < 128) {
        float a = 0.f;
        for (int e = 0; e < 128; e++) a += Wks[t*128 + e] * g1_s[e];
        g2_s[t] = a * 0.08838834764831845f;
    }
    __syncthreads();
    // P9: logits
    if (t < 200) {
        int c = t >> 1, ih = t & 1;
        float a = 0.f;
        for (int i = ih*64; i < ih*64 + 64; i++) a += g2_s[i] * clu[c*CSTRIDE + i];
        a += __shfl_xor(a, 1);
        if (!ih) lg[c] = vcm_s[c] ? NEGV : 10.0f * tanhf(a);
    }
    __syncthreads();
    // P10: log-softmax denom + first-occurrence argmax
    if (t < 32) {
        float bv = -1e30f; int bi = 0;
        for (int c = t; c < CC; c += 32) { float v = lg[c]; if (v > bv) { bv = v; bi = c; } }
        for (int o = 1; o < 32; o <<= 1) {
            float ov = __shfl_xor(bv, o); int oi = __shfl_xor(bi, o);
            if (ov > bv || (ov == bv && oi < bi)) { bv = ov; bi = oi; }
        }
        float se = 0.f;
        for (int c = t; c < CC; c += 32) se += expf(lg[c] - bv);
        for (int o = 1; o < 32; o <<= 1) se += __shfl_xor(se, o);
        if (t == 0) { g_idx = bi; lse_s = bv + logf(se); }
    }
    __syncthreads();

    // P11: outputs
    int gi = g_idx; float lse = lse_s;
    if (t < CC)  out[OUT_CP + b*CC + t] = lg[t] - lse;
    if (t == 0)  out[OUT_GU + b] = (float)gi;
    if (t < 128) {
        float ge = clu[gi*CSTRIDE + t];
        out[OUT_GE + b*DD + t] = ge;
        float uc = 0.f;
        for (int s = 0; s < NSPLIT; s++) uc += part2[(b*NSPLIT + s)*DD + t];
        out[OUT_AUG + b*512 +       t] = uc * (1.0f/2000.0f);
        out[OUT_AUG + b*512 + 128 + t] = current[b*DD + t];
        out[OUT_AUG + b*512 + 256 + t] = ge;
        out[OUT_AUG + b*512 + 384 + t] = depot[b*DD + t];
    }
}

extern "C" void kernel_launch(void* const* d_in, const int* in_sizes, int n_in,
                              void* d_out, int out_size, void* d_ws, size_t ws_size,
                              hipStream_t stream) {
    const float* depot   = (const float*)d_in[0];
    const float* cluster = (const float*)d_in[1];
    const float* current = (const float*)d_in[2];
    const float* node    = (const float*)d_in[3];
    const int*   is_new  = (const int*)d_in[4];
    const int*   cmask   = (const int*)d_in[5];
    const int*   visited = (const int*)d_in[6];
    const int*   mask    = (const int*)d_in[7];
    const float* Wq  = (const float*)d_in[8];
    const float* Wk  = (const float*)d_in[9];
    const float* Wv  = (const float*)d_in[10];
    const float* Wks = (const float*)d_in[11];
    const float* Wmq = (const float*)d_in[12];
    const float* Wmk = (const float*)d_in[13];
    const float* Wmv = (const float*)d_in[14];
    const float* Wmo = (const float*)d_in[15];
    float* ws  = (float*)d_ws;
    float* out = (float*)d_out;

    k_prep_sums<<<80 + BB*NSPLIT, 256, 0, stream>>>(node, mask, cmask, is_new,
                                                    Wq, Wmq, Wk, Wmk, Wv, Wmv, ws);
    k_fused<<<BB, 256, 0, stream>>>(cluster, current, depot, is_new, visited,
                                    Wks, Wmo, ws, out);
}